// Round 10
// baseline (708.243 us; speedup 1.0000x reference)
//
#include <hip/hip_runtime.h>
#include <hip/hip_bf16.h>
#include <math.h>

typedef unsigned short u16t;
typedef unsigned int   u32t;
typedef unsigned long long u64t;
typedef __attribute__((ext_vector_type(8))) short  short8;   // 8 bf16 (4 VGPRs)
typedef __attribute__((ext_vector_type(4))) float  floatx4;  // MFMA acc

#define NPTS   8192
#define DMODEL 256
#define BNTOT  16384
#define HSTR   264

__device__ __forceinline__ float bitsf(u32t u){ union { u32t i; float f; } v; v.i = u; return v.f; }
__device__ __forceinline__ float b2f(u16t s){ return bitsf(((u32t)s) << 16); }
__device__ __forceinline__ u16t f2b(float f){
  __hip_bfloat16 h = __float2bfloat16(f);
  return *reinterpret_cast<u16t*>(&h);
}
__device__ __forceinline__ uint4 pack8(const float* o){
  uint4 st;
  st.x = (u32t)f2b(o[0]) | ((u32t)f2b(o[1]) << 16);
  st.y = (u32t)f2b(o[2]) | ((u32t)f2b(o[3]) << 16);
  st.z = (u32t)f2b(o[4]) | ((u32t)f2b(o[5]) << 16);
  st.w = (u32t)f2b(o[6]) | ((u32t)f2b(o[7]) << 16);
  return st;
}

// Branchless erf-based exact GELU (A&S 7.1.26, |eps_erf| <= 1.5e-7)
__device__ __forceinline__ float gelu_fast(float x){
  float ax = fabsf(x) * 0.70710678118654752f;
  float t  = __builtin_amdgcn_rcpf(__builtin_fmaf(0.3275911f, ax, 1.0f));
  float p  = t*(0.254829592f + t*(-0.284496736f + t*(1.421413741f +
             t*(-1.453152027f + t*1.061405429f))));
  float er = __builtin_fmaf(-p, __expf(-ax*ax), 1.0f);
  return 0.5f * x * (1.0f + copysignf(er, x));
}

__global__ __launch_bounds__(256) void fill_valf(float* p, int n, float v){
  int i = blockIdx.x * 256 + threadIdx.x;
  if (i < n) p[i] = v;
}

// -------------------------------------------------- weight fragment prepack
// frag element ((ic*16+cca)*64 + lane)*8 + v = W[ic*32+(lane>>4)*8+v][cca*16+(lane&15)]
__global__ __launch_bounds__(256) void wprep4(const float* __restrict__ Wk,
                                              const float* __restrict__ Wv,
                                              const float* __restrict__ Wp2,
                                              const float* __restrict__ Wq,
                                              u16t* __restrict__ out) {
  int e = blockIdx.x * 256 + threadIdx.x;        // 0..262143
  int m = e >> 16, r = e & 65535;
  const float* W = (m == 0) ? Wk : (m == 1 ? Wv : (m == 2 ? Wp2 : Wq));
  int v = r & 7, l = (r >> 3) & 63, cca = (r >> 9) & 15, ic = r >> 13;
  int i = ic * 32 + (l >> 4) * 8 + v;
  int c = cca * 16 + (l & 15);
  out[e] = f2b(W[(size_t)i * DMODEL + c]);
}
__global__ __launch_bounds__(256) void wprep1(const float* __restrict__ W,
                                              u16t* __restrict__ out) {
  int r = blockIdx.x * 256 + threadIdx.x;        // 0..65535
  int v = r & 7, l = (r >> 3) & 63, cca = (r >> 9) & 15, ic = r >> 13;
  int i = ic * 32 + (l >> 4) * 8 + v;
  int c = cca * 16 + (l & 15);
  out[r] = f2b(W[(size_t)i * DMODEL + c]);
}

// ------------------------------------------------- kNN: bitonic helpers
__device__ __forceinline__ void cswap_asc(u64t& a, u64t& b){
  u64t mn = (a < b) ? a : b;
  u64t mx = (a < b) ? b : a;
  a = mn; b = mx;
}
__device__ __forceinline__ void bitonic16(u64t v[16]){
  #pragma unroll
  for (int k = 2; k <= 16; k <<= 1) {
    #pragma unroll
    for (int j = k >> 1; j > 0; j >>= 1) {
      #pragma unroll
      for (int i = 0; i < 16; ++i) {
        int l = i ^ j;
        if (l > i) {
          if ((i & k) == 0) cswap_asc(v[i], v[l]);   // ascending run
          else              cswap_asc(v[l], v[i]);   // descending run
        }
      }
    }
  }
}
// best (asc) + v (asc) -> best = 16 smallest, ascending
__device__ __forceinline__ void merge16(u64t best[16], u64t v[16]){
  #pragma unroll
  for (int i = 0; i < 16; ++i) {
    u64t o = v[15 - i];
    best[i] = (best[i] < o) ? best[i] : o;
  }
  #pragma unroll
  for (int j = 8; j > 0; j >>= 1) {
    #pragma unroll
    for (int i = 0; i < 16; ++i) {
      int l = i ^ j;
      if (l > i) cswap_asc(best[i], best[l]);
    }
  }
}
__device__ __forceinline__ void knn_flush(u64t best[16], float& thrf, int& cnt,
                                          const u64t* bufw, int lane){
  u64t v[16];
  #pragma unroll
  for (int s = 0; s < 16; ++s) {
    u64t x = bufw[s * 64 + lane];
    v[s] = (s < cnt) ? x : 0xFFFFFFFFFFFFFFFFULL;   // mask stale slots
  }
  bitonic16(v);
  merge16(best, v);
  u32t k15 = (u32t)(best[15] >> 32);
  thrf = (k15 == 0xFFFFFFFFu) ? 3.3e38f
       : bitsf((k15 & 0x80000000u) ? (k15 ^ 0x80000000u) : ~k15);
  cnt = 0;
}

// ---------------------------------------------------------------- kNN partial
// 8 chunks of 1024; batched-bitonic top-16 with u64 (distkey:idx) keys.
// R2 form verbatim (measured best).
__global__ __launch_bounds__(256) void knn_partial(const float* __restrict__ coords,
                                                   u64t* __restrict__ pk) {
  int qb = blockIdx.x >> 3, ch = blockIdx.x & 7;
  int tid = threadIdx.x;
  int lane = tid & 63, wv = tid >> 6;
  int g = qb * 256 + tid;
  int b = g >> 13;
  alignas(16) __shared__ float4 tile[256];
  __shared__ u64t buf[4][16][64];                  // [wave][slot][lane], 32 KB

  float qx = coords[(size_t)g * 3 + 0];
  float qy = coords[(size_t)g * 3 + 1];
  float qz = coords[(size_t)g * 3 + 2];
  float qd2 = __fadd_rn(__fadd_rn(__fmul_rn(qx,qx), __fmul_rn(qy,qy)), __fmul_rn(qz,qz));

  u64t best[16];
  #pragma unroll
  for (int s = 0; s < 16; ++s) best[s] = 0xFFFFFFFFFFFFFFFFULL;
  float thrf = 3.3e38f;
  int  cnt = 0;
  u64t* bufw = &buf[wv][0][0];

  int cs = ch * 1024;
  for (int t = 0; t < 4; ++t) {
    int ci = cs + t * 256 + tid;
    size_t cb = (size_t)(b * NPTS + ci) * 3;
    float x = coords[cb + 0];
    float y = coords[cb + 1];
    float z = coords[cb + 2];
    float d2 = __fadd_rn(__fadd_rn(__fmul_rn(x,x), __fmul_rn(y,y)), __fmul_rn(z,z));
    __syncthreads();
    tile[tid] = make_float4(x, y, z, d2);
    __syncthreads();
    int cbase = cs + t * 256;
    for (int u = 0; u < 256; ++u) {
      float4 cd = tile[u];
      float dot = __fadd_rn(__fadd_rn(__fmul_rn(qx,cd.x), __fmul_rn(qy,cd.y)), __fmul_rn(qz,cd.z));
      float dist = __fsub_rn(__fadd_rn(qd2, cd.w), __fmul_rn(2.0f, dot));
      if (dist <= thrf) {
        u32t db  = __float_as_uint(dist);
        u32t key = db ^ ((u32t)(((int)db) >> 31) | 0x80000000u);  // monotone map
        bufw[cnt * 64 + lane] = ((u64t)key << 32) | (u32t)(cbase + u);
        ++cnt;
      }
      if (__any(cnt == 16)) knn_flush(best, thrf, cnt, bufw, lane);
    }
  }
  if (__any(cnt > 0)) knn_flush(best, thrf, cnt, bufw, lane);

  size_t base = (size_t)g * 128 + ch * 16;
  #pragma unroll
  for (int s = 0; s < 16; ++s) pk[base + s] = best[s];
}

// ---------------------------------------------------------------- kNN merge
// 8 sorted u64-key lists of 16 -> global top-16 (stable via key low bits).
__global__ __launch_bounds__(256) void knn_merge(const u64t* __restrict__ pk,
                                                 u16t* __restrict__ idxb) {
  int g = blockIdx.x * 256 + threadIdx.x;
  size_t base = (size_t)g * 128;
  int h[8];
  #pragma unroll
  for (int c = 0; c < 8; ++c) h[c] = 0;
  for (int s = 0; s < 16; ++s) {
    u64t bk = 0xFFFFFFFFFFFFFFFFULL; int bc = 0;
    #pragma unroll
    for (int c = 0; c < 8; ++c) {
      if (h[c] < 16) {
        u64t kk = pk[base + c * 16 + h[c]];
        if (kk < bk) { bk = kk; bc = c; }
      }
    }
    idxb[(size_t)g * 16 + s] = (u16t)(bk & 0xFFFFu);
    h[bc]++;
  }
}

// ----------------------------------------------------------- K/V GEMM (MFMA)
// 512 blocks x 32 rows (2 blocks/CU): wave = one (mat, 16-row-group) pair.
__global__ __launch_bounds__(256) void gemm_kv_mfma(const float* __restrict__ feat,
    const u16t* __restrict__ frags,
    const float* __restrict__ bk, const float* __restrict__ bv,
    u16t* __restrict__ kb, u16t* __restrict__ vb) {
  int rbase = blockIdx.x * 32;
  int tid = threadIdx.x, lane = tid & 63, wvi = tid >> 6;
  int quad = lane >> 4, l15 = lane & 15;
  int mat = wvi >> 1, rg = wvi & 1;

  alignas(16) __shared__ u16t featS[32 * HSTR];

  {
    int r = tid >> 3, c0 = (tid & 7) * 32;        // 8 threads/row, 32 cols each
    const float* src = feat + (size_t)(rbase + r) * DMODEL + c0;
    u16t* dst = featS + r * HSTR + c0;
    #pragma unroll
    for (int t = 0; t < 4; ++t) {
      float4 a = *(const float4*)(src + t * 8);
      float4 b = *(const float4*)(src + t * 8 + 4);
      float o[8] = {a.x, a.y, a.z, a.w, b.x, b.y, b.z, b.w};
      *(uint4*)(dst + t * 8) = pack8(o);
    }
  }
  __syncthreads();

  short8 af[8];
  #pragma unroll
  for (int ic = 0; ic < 8; ++ic)
    af[ic] = *(const short8*)(featS + (rg * 16 + l15) * HSTR + ic * 32 + quad * 8);

  const u16t* wf    = frags + (size_t)mat * 65536;
  const float* bias = mat ? bv : bk;
  u16t* out         = mat ? vb : kb;

  floatx4 acc[16];
  #pragma unroll
  for (int ct = 0; ct < 16; ++ct) acc[ct] = (floatx4){0.f, 0.f, 0.f, 0.f};

  #pragma unroll
  for (int ic = 0; ic < 8; ++ic) {
    #pragma unroll
    for (int ct = 0; ct < 16; ++ct) {
      short8 bf = *(const short8*)(wf + (((size_t)(ic * 16 + ct) * 64 + lane) << 3));
      acc[ct] = __builtin_amdgcn_mfma_f32_16x16x32_bf16(af[ic], bf, acc[ct], 0, 0, 0);
    }
  }

  #pragma unroll
  for (int ct = 0; ct < 16; ++ct) {
    int col = ct * 16 + l15;
    float bvv = bias[col];
    #pragma unroll
    for (int r = 0; r < 4; ++r) {
      int row = rbase + rg * 16 + quad * 4 + r;
      out[(size_t)row * DMODEL + col] = f2b(acc[ct][r] + bvv);
    }
  }
}

// -------------------------------------------------------------- mega kernel
// v10 = v5's lock-step structure with 2-QUERY GROUPS (4 groups): hemb halves
// to 32 rows -> LDS 38.9 KB -> 21.4 KB -> 5+ blocks/CU (was 4, 45% occ).
// Gather phases are latency-bound (FETCH 237 MB at only 1 TB/s, 55% stall);
// occupancy is the lever. Logit phase: waves 0,1 handle the 2 queries.
__global__ __launch_bounds__(256, 5) void attn_mega(
    const float* __restrict__ coords, const float* __restrict__ normals,
    const float* __restrict__ maskp, const float* __restrict__ feat,
    const float* __restrict__ bq,
    const float* __restrict__ Wp1, const float* __restrict__ bp1,
    const float* __restrict__ bp2,
    const u16t* __restrict__ idxp,
    const u16t* __restrict__ wqfrag, const u16t* __restrict__ wp2frag,
    const u16t* __restrict__ kbuf, const u16t* __restrict__ vbuf,
    float* __restrict__ outp) {
  alignas(16) __shared__ u16t hemb[32 * HSTR];   // 16,896 B (2 queries x 16)
  alignas(16) __shared__ u16t qB[8 * HSTR];      //  4,224 B (q bf16, bq baked)
  __shared__ float wS[32];
  __shared__ int   idS[32];

  int c    = threadIdx.x;
  int lane = c & 63;
  int wv   = c >> 6;
  int quad = lane >> 4;
  int l15  = lane & 15;
  int wv4  = wv * 4;
  int qbase = blockIdx.x * 8;

  // ---- stage 8 feat rows as bf16 into rows 0..15 (rows 8..15 zeroed: pad)
  {
    int r = c >> 5, c0 = (c & 31) * 8;
    const float* src = feat + (size_t)(qbase + r) * DMODEL + c0;
    float4 a = *(const float4*)(src);
    float4 b = *(const float4*)(src + 4);
    float o[8] = {a.x, a.y, a.z, a.w, b.x, b.y, b.z, b.w};
    *(uint4*)(hemb + r * HSTR + c0) = pack8(o);
    uint4 z; z.x = 0u; z.y = 0u; z.z = 0u; z.w = 0u;
    *(uint4*)(hemb + (8 + r) * HSTR + c0) = z;
  }
  __syncthreads();

  // ---- Q projection via MFMA -> qB bf16 (bq baked)
  {
    floatx4 qa[4];
    #pragma unroll
    for (int cc = 0; cc < 4; ++cc) qa[cc] = (floatx4){0.f, 0.f, 0.f, 0.f};
    #pragma unroll
    for (int ic = 0; ic < 8; ++ic) {
      short8 af = *(const short8*)(hemb + l15 * HSTR + ic * 32 + quad * 8);
      #pragma unroll
      for (int cc = 0; cc < 4; ++cc) {
        short8 bf = *(const short8*)(wqfrag + (((size_t)(ic * 16 + wv4 + cc) * 64 + lane) << 3));
        qa[cc] = __builtin_amdgcn_mfma_f32_16x16x32_bf16(af, bf, qa[cc], 0, 0, 0);
      }
    }
    if (quad < 2) {
      #pragma unroll
      for (int cc = 0; cc < 4; ++cc) {
        int col = (wv4 + cc) * 16 + l15;
        float bqv = bq[col];
        #pragma unroll
        for (int r = 0; r < 4; ++r)
          qB[(quad * 4 + r) * HSTR + col] = f2b(qa[cc][r] + bqv);
      }
    }
  }

  float w1[6];
  #pragma unroll
  for (int p = 0; p < 6; ++p) w1[p] = Wp1[p * DMODEL + c];
  float b1v = bp1[c];
  float b2c[4];
  #pragma unroll
  for (int cc = 0; cc < 4; ++cc) b2c[cc] = bp2[(wv4 + cc) * 16 + l15];
  const float lsc = 0.17677669529663687f;
  __syncthreads();   // qB visible; hemb feat rows free

  for (int G = 0; G < 4; ++G) {
    // ---- pos MLP layer 1 + GELU for 2 queries -> hemb rows 0..31
    #pragma unroll
    for (int ql = 0; ql < 2; ++ql) {
      int g = qbase + G * 2 + ql;
      int bb0 = (g >> 13) * NPTS;
      float qx = coords[(size_t)g * 3 + 0];
      float qy = coords[(size_t)g * 3 + 1];
      float qz = coords[(size_t)g * 3 + 2];
      float n0 = normals[(size_t)g * 3 + 0];
      float n1 = normals[(size_t)g * 3 + 1];
      float n2 = normals[(size_t)g * 3 + 2];
      #pragma unroll
      for (int j = 0; j < 16; ++j) {
        int id = (int)idxp[(size_t)g * 16 + j];
        size_t cb = (size_t)(bb0 + id) * 3;
        float rx = qx - coords[cb + 0];
        float ry = qy - coords[cb + 1];
        float rz = qz - coords[cb + 2];
        float pre = b1v + rx * w1[0] + ry * w1[1] + rz * w1[2]
                        + n0 * w1[3] + n1 * w1[4] + n2 * w1[5];
        hemb[(ql * 16 + j) * HSTR + c] = f2b(gelu_fast(pre));
      }
    }
    __syncthreads();   // (b)

    // ---- pos MLP layer 2: 32-row MFMA pass (B-frags amortized 2x)
    {
      floatx4 acc[2][4];
      #pragma unroll
      for (int rt = 0; rt < 2; ++rt)
        #pragma unroll
        for (int cc = 0; cc < 4; ++cc) acc[rt][cc] = (floatx4){0.f, 0.f, 0.f, 0.f};

      #pragma unroll
      for (int ic = 0; ic < 8; ++ic) {
        short8 af0 = *(const short8*)(hemb + ( 0 + l15) * HSTR + ic * 32 + quad * 8);
        short8 af1 = *(const short8*)(hemb + (16 + l15) * HSTR + ic * 32 + quad * 8);
        #pragma unroll
        for (int cc = 0; cc < 4; ++cc) {
          short8 bf = *(const short8*)(wp2frag + (((size_t)(ic * 16 + wv4 + cc) * 64 + lane) << 3));
          acc[0][cc] = __builtin_amdgcn_mfma_f32_16x16x32_bf16(af0, bf, acc[0][cc], 0, 0, 0);
          acc[1][cc] = __builtin_amdgcn_mfma_f32_16x16x32_bf16(af1, bf, acc[1][cc], 0, 0, 0);
        }
      }
      __syncthreads();   // (c) all A-frag reads complete before emb overwrite
      #pragma unroll
      for (int rt = 0; rt < 2; ++rt)
        #pragma unroll
        for (int cc = 0; cc < 4; ++cc) {
          int cg = (wv4 + cc) * 16 + l15;
          #pragma unroll
          for (int r = 0; r < 4; ++r)
            hemb[(rt * 16 + quad * 4 + r) * HSTR + cg] = f2b(acc[rt][cc][r] + b2c[cc]);
        }
    }
    __syncthreads();   // (d) emb ready

    // ---- logits via MFMA: waves 0,1 handle queries G*2+{0,1}
    if (wv < 2) {
      int g = qbase + G * 2 + wv;
      int bb0 = (g >> 13) * NPTS;
      int idl = (int)idxp[(size_t)g * 16 + l15];
      float mvl = maskp[bb0 + idl];
      unsigned long long bm = __ballot(mvl > 0.0f);
      if (quad == 0) idS[wv * 16 + l15] = idl;
      const u16t* krow = kbuf + (size_t)(bb0 + idl) * DMODEL;
      const u16t* erow = hemb + (wv * 16 + l15) * HSTR;
      const u16t* qrow = qB + (G * 2 + wv) * HSTR;
      floatx4 sa = (floatx4){0.f, 0.f, 0.f, 0.f};
      #pragma unroll
      for (int ic = 0; ic < 8; ++ic) {
        short8 ak  = *(const short8*)(krow + ic * 32 + quad * 8);
        short8 ae  = *(const short8*)(erow + ic * 32 + quad * 8);
        short8 qb8 = *(const short8*)(qrow + ic * 32 + quad * 8);
        sa = __builtin_amdgcn_mfma_f32_16x16x32_bf16(ak, qb8, sa, 0, 0, 0);
        sa = __builtin_amdgcn_mfma_f32_16x16x32_bf16(ae, qb8, sa, 0, 0, 0);
      }
      float lg[4];
      #pragma unroll
      for (int r = 0; r < 4; ++r) {
        int j = quad * 4 + r;
        lg[r] = ((bm >> j) & 1ULL) ? sa[r] * lsc : -1e30f;
      }
      float m = fmaxf(fmaxf(lg[0], lg[1]), fmaxf(lg[2], lg[3]));
      m = fmaxf(m, __shfl_xor(m, 16));
      m = fmaxf(m, __shfl_xor(m, 32));
      float e0 = __expf(lg[0] - m), e1 = __expf(lg[1] - m);
      float e2 = __expf(lg[2] - m), e3 = __expf(lg[3] - m);
      float s = e0 + e1 + e2 + e3;
      s += __shfl_xor(s, 16);
      s += __shfl_xor(s, 32);
      float inv = (m > -1e29f) ? __builtin_amdgcn_rcpf(s) : 0.0f;
      if (l15 == 0) {
        wS[wv * 16 + quad * 4 + 0] = e0 * inv;
        wS[wv * 16 + quad * 4 + 1] = e1 * inv;
        wS[wv * 16 + quad * 4 + 2] = e2 * inv;
        wS[wv * 16 + quad * 4 + 3] = e3 * inv;
      }
    }
    __syncthreads();   // (e) weights + ids ready

    // ---- PV per-thread (d = c), 2 queries
    #pragma unroll
    for (int ql = 0; ql < 2; ++ql) {
      int g = qbase + G * 2 + ql;
      int bb0 = (g >> 13) * NPTS;
      float o = 0.0f;
      #pragma unroll
      for (int j = 0; j < 16; ++j) {
        int id  = idS[ql * 16 + j];
        float w = wS[ql * 16 + j];
        float vv = b2f(vbuf[(size_t)(bb0 + id) * DMODEL + c]);
        float ee = b2f(hemb[(ql * 16 + j) * HSTR + c]);
        o += w * (vv + ee);
      }
      outp[(size_t)g * DMODEL + c] = o;
    }
    if (G < 3) __syncthreads();   // (a') hemb reads done before next gelu
  }
}

// --------------------------------------------- out projection + LayerNorm
__global__ __launch_bounds__(256) void gemm_out(const float* __restrict__ feat,
    const float* __restrict__ maskp,
    const u16t* __restrict__ wofrag, const float* __restrict__ bo,
    const float* __restrict__ gamma, const float* __restrict__ beta,
    float* __restrict__ io) {
  int rbase = blockIdx.x * 64;
  int tid = threadIdx.x, lane = tid & 63, wvi = tid >> 6;
  int quad = lane >> 4, l15 = lane & 15;

  alignas(16) __shared__ u16t oS[64 * HSTR];

  {
    int r = tid >> 2, c0 = (tid & 3) * 64;
    const float* src = io + (size_t)(rbase + r) * DMODEL + c0;
    u16t* dst = oS + r * HSTR + c0;
    #pragma unroll
    for (int t = 0; t < 8; ++t) {
      float4 a = *(const float4*)(src + t * 8);
      float4 b = *(const float4*)(src + t * 8 + 4);
      float o[8] = {a.x, a.y, a.z, a.w, b.x, b.y, b.z, b.w};
      *(uint4*)(dst + t * 8) = pack8(o);
    }
  }
  __syncthreads();

  floatx4 acc[16];
  #pragma unroll
  for (int ct = 0; ct < 16; ++ct) acc[ct] = (floatx4){0.f, 0.f, 0.f, 0.f};

  #pragma unroll
  for (int ic = 0; ic < 8; ++ic) {
    short8 af = *(const short8*)(oS + (wvi * 16 + l15) * HSTR + ic * 32 + quad * 8);
    #pragma unroll
    for (int ct = 0; ct < 16; ++ct) {
      short8 bf = *(const short8*)(wofrag + (((size_t)(ic * 16 + ct) * 64 + lane) << 3));
      acc[ct] = __builtin_amdgcn_mfma_f32_16x16x32_bf16(af, bf, acc[ct], 0, 0, 0);
    }
  }

  float bov[16], gamv[16], betv[16];
  #pragma unroll
  for (int ct = 0; ct < 16; ++ct) {
    int col = ct * 16 + l15;
    bov[ct]  = bo[col];
    gamv[ct] = gamma[col];
    betv[ct] = beta[col];
  }

  #pragma unroll
  for (int r = 0; r < 4; ++r) {
    int row = rbase + wvi * 16 + quad * 4 + r;
    float mv = maskp[row];
    float hv[16];
    float s = 0.0f, s2 = 0.0f;
    #pragma unroll
    for (int ct = 0; ct < 16; ++ct) {
      float h = feat[(size_t)row * DMODEL + ct * 16 + l15] + (acc[ct][r] + bov[ct]) * mv;
      hv[ct] = h; s += h; s2 += h * h;
    }
    #pragma unroll
    for (int off = 1; off < 16; off <<= 1) {
      s  += __shfl_xor(s,  off, 16);
      s2 += __shfl_xor(s2, off, 16);
    }
    float mu  = s  * (1.0f / 256.0f);
    float ms  = s2 * (1.0f / 256.0f);
    float var = ms - mu * mu;
    float inv = 1.0f / sqrtf(var + 1e-6f);
    #pragma unroll
    for (int ct = 0; ct < 16; ++ct) {
      float y = (hv[ct] - mu) * inv * gamv[ct] + betv[ct];
      y *= mv;
      io[(size_t)row * DMODEL + ct * 16 + l15] = y;
    }
  }
}

// ---------------------------------------------------------------------- host
extern "C" void kernel_launch(void* const* d_in, const int* in_sizes, int n_in,
                              void* d_out, int out_size, void* d_ws, size_t ws_size,
                              hipStream_t stream) {
  static const int EXP[18] = {4194304, 49152, 49152, 16384,
                              65536, 256, 65536, 256, 65536, 256, 65536, 256,
                              1536, 256, 65536, 256, 256, 256};
  bool sizes_ok = (n_in >= 18);
  if (sizes_ok) for (int i = 0; i < 18; ++i) sizes_ok = sizes_ok && (in_sizes[i] == EXP[i]);
  int fb = (out_size + 255) / 256;
  if (!sizes_ok) {
    fill_valf<<<fb, 256, 0, stream>>>((float*)d_out, out_size, 0.0f);
    return;
  }
  const size_t WS_NEED = 17825792;
  if (ws_size < WS_NEED) {
    fill_valf<<<fb, 256, 0, stream>>>((float*)d_out, out_size, 1.0f);
    return;
  }

  const float* feat    = (const float*)d_in[0];
  const float* coords  = (const float*)d_in[1];
  const float* normals = (const float*)d_in[2];
  const float* maskp   = (const float*)d_in[3];
  const float* Wq  = (const float*)d_in[4];
  const float* bq  = (const float*)d_in[5];
  const float* Wk  = (const float*)d_in[6];
  const float* bk  = (const float*)d_in[7];
  const float* Wv  = (const float*)d_in[8];
  const float* bv  = (const float*)d_in[9];
  const float* Wo  = (const float*)d_in[10];
  const float* bo  = (const float*)d_in[11];
  const float* Wp1 = (const float*)d_in[12];
  const float* bp1 = (const float*)d_in[13];
  const float* Wp2 = (const float*)d_in[14];
  const float* bp2 = (const float*)d_in[15];
  const float* gamma = (const float*)d_in[16];
  const float* beta  = (const float*)d_in[17];

  // Workspace (= 17,825,792 B exactly):
  //   idx16 : u16 [16384*16]      @ 0          (524,288)
  //   frags : bf16 [4*65536]      @ 524,288    (524,288)  (Wk,Wv,Wp2,Wq)
  //   kb    : bf16 [16384*256]    @ 1,048,576  (8,388,608)
  //   vb    : bf16 [16384*256]    @ 9,437,184  (8,388,608)  end 17,825,792
  //   pk (kNN u64 partials, 16 MB) aliases kb+vb: dead before gemm_kv_mfma.
  //   wofrag (Wo frags, 128 KB) aliases kb: packed AFTER attn_mega (kb dead).
  char* ws = (char*)d_ws;
  u16t*  idx16  = (u16t*)(ws);
  u16t*  frags  = (u16t*)(ws + 524288);
  u16t*  kb     = (u16t*)(ws + 1048576);
  u16t*  vb     = (u16t*)(ws + 9437184);
  u64t*  pk     = (u64t*)(ws + 1048576);
  u16t*  wofrag = (u16t*)(ws + 1048576);

  wprep4<<<1024, 256, 0, stream>>>(Wk, Wv, Wp2, Wq, frags);
  knn_partial<<<512, 256, 0, stream>>>(coords, pk);
  knn_merge<<<64, 256, 0, stream>>>(pk, idx16);
  gemm_kv_mfma<<<512, 256, 0, stream>>>(feat, frags, bk, bv, kb, vb);
  attn_mega<<<2048, 256, 0, stream>>>(coords, normals, maskp, feat,
                                      bq, Wp1, bp1, bp2,
                                      idx16, frags + 196608, frags + 131072,
                                      kb, vb, (float*)d_out);
  wprep1<<<256, 256, 0, stream>>>(Wo, wofrag);   // kb dead after attn_mega
  gemm_out<<<256, 256, 0, stream>>>(feat, maskp, wofrag, bo, gamma, beta,
                                    (float*)d_out);
}

// Round 11
// 529.613 us; speedup vs baseline: 1.3373x; 1.3373x over previous
//
#include <hip/hip_runtime.h>
#include <hip/hip_bf16.h>
#include <math.h>

typedef unsigned short u16t;
typedef unsigned int   u32t;
typedef unsigned long long u64t;
typedef __attribute__((ext_vector_type(8))) short  short8;   // 8 bf16 (4 VGPRs)
typedef __attribute__((ext_vector_type(4))) float  floatx4;  // MFMA acc

#define NPTS   8192
#define DMODEL 256
#define BNTOT  16384
#define HSTR   264

__device__ __forceinline__ float bitsf(u32t u){ union { u32t i; float f; } v; v.i = u; return v.f; }
__device__ __forceinline__ float b2f(u16t s){ return bitsf(((u32t)s) << 16); }
__device__ __forceinline__ u16t f2b(float f){
  __hip_bfloat16 h = __float2bfloat16(f);
  return *reinterpret_cast<u16t*>(&h);
}
__device__ __forceinline__ uint4 pack8(const float* o){
  uint4 st;
  st.x = (u32t)f2b(o[0]) | ((u32t)f2b(o[1]) << 16);
  st.y = (u32t)f2b(o[2]) | ((u32t)f2b(o[3]) << 16);
  st.z = (u32t)f2b(o[4]) | ((u32t)f2b(o[5]) << 16);
  st.w = (u32t)f2b(o[6]) | ((u32t)f2b(o[7]) << 16);
  return st;
}

// Branchless erf-based exact GELU (A&S 7.1.26, |eps_erf| <= 1.5e-7)
__device__ __forceinline__ float gelu_fast(float x){
  float ax = fabsf(x) * 0.70710678118654752f;
  float t  = __builtin_amdgcn_rcpf(__builtin_fmaf(0.3275911f, ax, 1.0f));
  float p  = t*(0.254829592f + t*(-0.284496736f + t*(1.421413741f +
             t*(-1.453152027f + t*1.061405429f))));
  float er = __builtin_fmaf(-p, __expf(-ax*ax), 1.0f);
  return 0.5f * x * (1.0f + copysignf(er, x));
}

__global__ __launch_bounds__(256) void fill_valf(float* p, int n, float v){
  int i = blockIdx.x * 256 + threadIdx.x;
  if (i < n) p[i] = v;
}

// -------------------------------------------------- weight fragment prepack
// frag element ((ic*16+cca)*64 + lane)*8 + v = W[ic*32+(lane>>4)*8+v][cca*16+(lane&15)]
__global__ __launch_bounds__(256) void wprep4(const float* __restrict__ Wk,
                                              const float* __restrict__ Wv,
                                              const float* __restrict__ Wp2,
                                              const float* __restrict__ Wq,
                                              u16t* __restrict__ out) {
  int e = blockIdx.x * 256 + threadIdx.x;        // 0..262143
  int m = e >> 16, r = e & 65535;
  const float* W = (m == 0) ? Wk : (m == 1 ? Wv : (m == 2 ? Wp2 : Wq));
  int v = r & 7, l = (r >> 3) & 63, cca = (r >> 9) & 15, ic = r >> 13;
  int i = ic * 32 + (l >> 4) * 8 + v;
  int c = cca * 16 + (l & 15);
  out[e] = f2b(W[(size_t)i * DMODEL + c]);
}
__global__ __launch_bounds__(256) void wprep1(const float* __restrict__ W,
                                              u16t* __restrict__ out) {
  int r = blockIdx.x * 256 + threadIdx.x;        // 0..65535
  int v = r & 7, l = (r >> 3) & 63, cca = (r >> 9) & 15, ic = r >> 13;
  int i = ic * 32 + (l >> 4) * 8 + v;
  int c = cca * 16 + (l & 15);
  out[r] = f2b(W[(size_t)i * DMODEL + c]);
}

// ------------------------------------------------- kNN: bitonic helpers
__device__ __forceinline__ void cswap_asc(u64t& a, u64t& b){
  u64t mn = (a < b) ? a : b;
  u64t mx = (a < b) ? b : a;
  a = mn; b = mx;
}
__device__ __forceinline__ void bitonic16(u64t v[16]){
  #pragma unroll
  for (int k = 2; k <= 16; k <<= 1) {
    #pragma unroll
    for (int j = k >> 1; j > 0; j >>= 1) {
      #pragma unroll
      for (int i = 0; i < 16; ++i) {
        int l = i ^ j;
        if (l > i) {
          if ((i & k) == 0) cswap_asc(v[i], v[l]);   // ascending run
          else              cswap_asc(v[l], v[i]);   // descending run
        }
      }
    }
  }
}
// best (asc) + v (asc) -> best = 16 smallest, ascending
__device__ __forceinline__ void merge16(u64t best[16], u64t v[16]){
  #pragma unroll
  for (int i = 0; i < 16; ++i) {
    u64t o = v[15 - i];
    best[i] = (best[i] < o) ? best[i] : o;
  }
  #pragma unroll
  for (int j = 8; j > 0; j >>= 1) {
    #pragma unroll
    for (int i = 0; i < 16; ++i) {
      int l = i ^ j;
      if (l > i) cswap_asc(best[i], best[l]);
    }
  }
}
__device__ __forceinline__ void knn_flush(u64t best[16], float& thrf, int& cnt,
                                          const u64t* bufw, int lane){
  u64t v[16];
  #pragma unroll
  for (int s = 0; s < 16; ++s) {
    u64t x = bufw[s * 64 + lane];
    v[s] = (s < cnt) ? x : 0xFFFFFFFFFFFFFFFFULL;   // mask stale slots
  }
  bitonic16(v);
  merge16(best, v);
  u32t k15 = (u32t)(best[15] >> 32);
  thrf = (k15 == 0xFFFFFFFFu) ? 3.3e38f
       : bitsf((k15 & 0x80000000u) ? (k15 ^ 0x80000000u) : ~k15);
  cnt = 0;
}

// ---------------------------------------------------------------- kNN partial
// 8 chunks of 1024; batched-bitonic top-16 with u64 (distkey:idx) keys.
// R2 form verbatim (measured best).
__global__ __launch_bounds__(256) void knn_partial(const float* __restrict__ coords,
                                                   u64t* __restrict__ pk) {
  int qb = blockIdx.x >> 3, ch = blockIdx.x & 7;
  int tid = threadIdx.x;
  int lane = tid & 63, wv = tid >> 6;
  int g = qb * 256 + tid;
  int b = g >> 13;
  alignas(16) __shared__ float4 tile[256];
  __shared__ u64t buf[4][16][64];                  // [wave][slot][lane], 32 KB

  float qx = coords[(size_t)g * 3 + 0];
  float qy = coords[(size_t)g * 3 + 1];
  float qz = coords[(size_t)g * 3 + 2];
  float qd2 = __fadd_rn(__fadd_rn(__fmul_rn(qx,qx), __fmul_rn(qy,qy)), __fmul_rn(qz,qz));

  u64t best[16];
  #pragma unroll
  for (int s = 0; s < 16; ++s) best[s] = 0xFFFFFFFFFFFFFFFFULL;
  float thrf = 3.3e38f;
  int  cnt = 0;
  u64t* bufw = &buf[wv][0][0];

  int cs = ch * 1024;
  for (int t = 0; t < 4; ++t) {
    int ci = cs + t * 256 + tid;
    size_t cb = (size_t)(b * NPTS + ci) * 3;
    float x = coords[cb + 0];
    float y = coords[cb + 1];
    float z = coords[cb + 2];
    float d2 = __fadd_rn(__fadd_rn(__fmul_rn(x,x), __fmul_rn(y,y)), __fmul_rn(z,z));
    __syncthreads();
    tile[tid] = make_float4(x, y, z, d2);
    __syncthreads();
    int cbase = cs + t * 256;
    for (int u = 0; u < 256; ++u) {
      float4 cd = tile[u];
      float dot = __fadd_rn(__fadd_rn(__fmul_rn(qx,cd.x), __fmul_rn(qy,cd.y)), __fmul_rn(qz,cd.z));
      float dist = __fsub_rn(__fadd_rn(qd2, cd.w), __fmul_rn(2.0f, dot));
      if (dist <= thrf) {
        u32t db  = __float_as_uint(dist);
        u32t key = db ^ ((u32t)(((int)db) >> 31) | 0x80000000u);  // monotone map
        bufw[cnt * 64 + lane] = ((u64t)key << 32) | (u32t)(cbase + u);
        ++cnt;
      }
      if (__any(cnt == 16)) knn_flush(best, thrf, cnt, bufw, lane);
    }
  }
  if (__any(cnt > 0)) knn_flush(best, thrf, cnt, bufw, lane);

  size_t base = (size_t)g * 128 + ch * 16;
  #pragma unroll
  for (int s = 0; s < 16; ++s) pk[base + s] = best[s];
}

// ---------------------------------------------------------------- kNN merge
// 8 sorted u64-key lists of 16 -> global top-16 (stable via key low bits).
__global__ __launch_bounds__(256) void knn_merge(const u64t* __restrict__ pk,
                                                 u16t* __restrict__ idxb) {
  int g = blockIdx.x * 256 + threadIdx.x;
  size_t base = (size_t)g * 128;
  int h[8];
  #pragma unroll
  for (int c = 0; c < 8; ++c) h[c] = 0;
  for (int s = 0; s < 16; ++s) {
    u64t bk = 0xFFFFFFFFFFFFFFFFULL; int bc = 0;
    #pragma unroll
    for (int c = 0; c < 8; ++c) {
      if (h[c] < 16) {
        u64t kk = pk[base + c * 16 + h[c]];
        if (kk < bk) { bk = kk; bc = c; }
      }
    }
    idxb[(size_t)g * 16 + s] = (u16t)(bk & 0xFFFFu);
    h[bc]++;
  }
}

// ----------------------------------------------------------- K/V GEMM (MFMA)
// 512 blocks x 32 rows (2 blocks/CU): wave = one (mat, 16-row-group) pair.
__global__ __launch_bounds__(256) void gemm_kv_mfma(const float* __restrict__ feat,
    const u16t* __restrict__ frags,
    const float* __restrict__ bk, const float* __restrict__ bv,
    u16t* __restrict__ kb, u16t* __restrict__ vb) {
  int rbase = blockIdx.x * 32;
  int tid = threadIdx.x, lane = tid & 63, wvi = tid >> 6;
  int quad = lane >> 4, l15 = lane & 15;
  int mat = wvi >> 1, rg = wvi & 1;

  alignas(16) __shared__ u16t featS[32 * HSTR];

  {
    int r = tid >> 3, c0 = (tid & 7) * 32;        // 8 threads/row, 32 cols each
    const float* src = feat + (size_t)(rbase + r) * DMODEL + c0;
    u16t* dst = featS + r * HSTR + c0;
    #pragma unroll
    for (int t = 0; t < 4; ++t) {
      float4 a = *(const float4*)(src + t * 8);
      float4 b = *(const float4*)(src + t * 8 + 4);
      float o[8] = {a.x, a.y, a.z, a.w, b.x, b.y, b.z, b.w};
      *(uint4*)(dst + t * 8) = pack8(o);
    }
  }
  __syncthreads();

  short8 af[8];
  #pragma unroll
  for (int ic = 0; ic < 8; ++ic)
    af[ic] = *(const short8*)(featS + (rg * 16 + l15) * HSTR + ic * 32 + quad * 8);

  const u16t* wf    = frags + (size_t)mat * 65536;
  const float* bias = mat ? bv : bk;
  u16t* out         = mat ? vb : kb;

  floatx4 acc[16];
  #pragma unroll
  for (int ct = 0; ct < 16; ++ct) acc[ct] = (floatx4){0.f, 0.f, 0.f, 0.f};

  #pragma unroll
  for (int ic = 0; ic < 8; ++ic) {
    #pragma unroll
    for (int ct = 0; ct < 16; ++ct) {
      short8 bf = *(const short8*)(wf + (((size_t)(ic * 16 + ct) * 64 + lane) << 3));
      acc[ct] = __builtin_amdgcn_mfma_f32_16x16x32_bf16(af[ic], bf, acc[ct], 0, 0, 0);
    }
  }

  #pragma unroll
  for (int ct = 0; ct < 16; ++ct) {
    int col = ct * 16 + l15;
    float bvv = bias[col];
    #pragma unroll
    for (int r = 0; r < 4; ++r) {
      int row = rbase + rg * 16 + quad * 4 + r;
      out[(size_t)row * DMODEL + col] = f2b(acc[ct][r] + bvv);
    }
  }
}

// -------------------------------------------------------------- mega kernel
// v5 VERBATIM (measured optimum: 213-236 µs). Block-synchronous group loop,
// logits via MFMA, in-LDS handoff. v6..v10 variants all regressed:
// wave-decoupling (spill), reg prefetch (spill), 2-query groups (FETCH 3x,
// occupancy unchanged — not LDS-limited at 4 blocks/CU).
__global__ __launch_bounds__(256, 4) void attn_mega(
    const float* __restrict__ coords, const float* __restrict__ normals,
    const float* __restrict__ maskp, const float* __restrict__ feat,
    const float* __restrict__ bq,
    const float* __restrict__ Wp1, const float* __restrict__ bp1,
    const float* __restrict__ bp2,
    const u16t* __restrict__ idxp,
    const u16t* __restrict__ wqfrag, const u16t* __restrict__ wp2frag,
    const u16t* __restrict__ kbuf, const u16t* __restrict__ vbuf,
    float* __restrict__ outp) {
  alignas(16) __shared__ u16t hemb[64 * HSTR];   // 33,792 B
  alignas(16) __shared__ u16t qB[8 * HSTR];      //  4,224 B (q bf16, bq baked)
  __shared__ float wS[64];
  __shared__ int   idS[64];

  int c    = threadIdx.x;
  int lane = c & 63;
  int wv   = c >> 6;
  int quad = lane >> 4;
  int l15  = lane & 15;
  int wv4  = wv * 4;
  int qbase = blockIdx.x * 8;

  // ---- stage 8 feat rows as bf16 (rows 8..15 zeroed: MFMA pad)
  {
    int r = c >> 5, c0 = (c & 31) * 8;
    const float* src = feat + (size_t)(qbase + r) * DMODEL + c0;
    float4 a = *(const float4*)(src);
    float4 b = *(const float4*)(src + 4);
    float o[8] = {a.x, a.y, a.z, a.w, b.x, b.y, b.z, b.w};
    *(uint4*)(hemb + r * HSTR + c0) = pack8(o);
    uint4 z; z.x = 0u; z.y = 0u; z.z = 0u; z.w = 0u;
    *(uint4*)(hemb + (8 + r) * HSTR + c0) = z;
  }
  __syncthreads();

  // ---- Q projection via MFMA -> qB bf16 (bq baked)
  {
    floatx4 qa[4];
    #pragma unroll
    for (int cc = 0; cc < 4; ++cc) qa[cc] = (floatx4){0.f, 0.f, 0.f, 0.f};
    #pragma unroll
    for (int ic = 0; ic < 8; ++ic) {
      short8 af = *(const short8*)(hemb + l15 * HSTR + ic * 32 + quad * 8);
      #pragma unroll
      for (int cc = 0; cc < 4; ++cc) {
        short8 bf = *(const short8*)(wqfrag + (((size_t)(ic * 16 + wv4 + cc) * 64 + lane) << 3));
        qa[cc] = __builtin_amdgcn_mfma_f32_16x16x32_bf16(af, bf, qa[cc], 0, 0, 0);
      }
    }
    if (quad < 2) {
      #pragma unroll
      for (int cc = 0; cc < 4; ++cc) {
        int col = (wv4 + cc) * 16 + l15;
        float bqv = bq[col];
        #pragma unroll
        for (int r = 0; r < 4; ++r)
          qB[(quad * 4 + r) * HSTR + col] = f2b(qa[cc][r] + bqv);
      }
    }
  }

  float w1[6];
  #pragma unroll
  for (int p = 0; p < 6; ++p) w1[p] = Wp1[p * DMODEL + c];
  float b1v = bp1[c];
  float b2c[4];
  #pragma unroll
  for (int cc = 0; cc < 4; ++cc) b2c[cc] = bp2[(wv4 + cc) * 16 + l15];
  const float lsc = 0.17677669529663687f;
  __syncthreads();   // qB visible; hemb feat rows free

  #pragma unroll
  for (int G = 0; G < 2; ++G) {
    // ---- pos MLP layer 1 + GELU for 4 queries -> hemb rows 0..63
    for (int ql = 0; ql < 4; ++ql) {
      int g = qbase + G * 4 + ql;
      int bb0 = (g >> 13) * NPTS;
      float qx = coords[(size_t)g * 3 + 0];
      float qy = coords[(size_t)g * 3 + 1];
      float qz = coords[(size_t)g * 3 + 2];
      float n0 = normals[(size_t)g * 3 + 0];
      float n1 = normals[(size_t)g * 3 + 1];
      float n2 = normals[(size_t)g * 3 + 2];
      #pragma unroll
      for (int j = 0; j < 16; ++j) {
        int id = (int)idxp[(size_t)g * 16 + j];
        size_t cb = (size_t)(bb0 + id) * 3;
        float rx = qx - coords[cb + 0];
        float ry = qy - coords[cb + 1];
        float rz = qz - coords[cb + 2];
        float pre = b1v + rx * w1[0] + ry * w1[1] + rz * w1[2]
                        + n0 * w1[3] + n1 * w1[4] + n2 * w1[5];
        hemb[(ql * 16 + j) * HSTR + c] = f2b(gelu_fast(pre));
      }
    }
    __syncthreads();   // (b)

    // ---- pos MLP layer 2: 64-row MFMA pass; bake bp2 into emb
    floatx4 acc[4][4];
    #pragma unroll
    for (int rt = 0; rt < 4; ++rt)
      #pragma unroll
      for (int cc = 0; cc < 4; ++cc) acc[rt][cc] = (floatx4){0.f, 0.f, 0.f, 0.f};

    #pragma unroll
    for (int ic = 0; ic < 8; ++ic) {
      short8 af0 = *(const short8*)(hemb + ( 0 + l15) * HSTR + ic * 32 + quad * 8);
      short8 af1 = *(const short8*)(hemb + (16 + l15) * HSTR + ic * 32 + quad * 8);
      short8 af2 = *(const short8*)(hemb + (32 + l15) * HSTR + ic * 32 + quad * 8);
      short8 af3 = *(const short8*)(hemb + (48 + l15) * HSTR + ic * 32 + quad * 8);
      #pragma unroll
      for (int cc = 0; cc < 4; ++cc) {
        short8 bf = *(const short8*)(wp2frag + (((size_t)(ic * 16 + wv4 + cc) * 64 + lane) << 3));
        acc[0][cc] = __builtin_amdgcn_mfma_f32_16x16x32_bf16(af0, bf, acc[0][cc], 0, 0, 0);
        acc[1][cc] = __builtin_amdgcn_mfma_f32_16x16x32_bf16(af1, bf, acc[1][cc], 0, 0, 0);
        acc[2][cc] = __builtin_amdgcn_mfma_f32_16x16x32_bf16(af2, bf, acc[2][cc], 0, 0, 0);
        acc[3][cc] = __builtin_amdgcn_mfma_f32_16x16x32_bf16(af3, bf, acc[3][cc], 0, 0, 0);
      }
    }
    __syncthreads();   // (c)
    #pragma unroll
    for (int rt = 0; rt < 4; ++rt)
      #pragma unroll
      for (int cc = 0; cc < 4; ++cc) {
        int cg = (wv4 + cc) * 16 + l15;
        #pragma unroll
        for (int r = 0; r < 4; ++r)
          hemb[(rt * 16 + quad * 4 + r) * HSTR + cg] = f2b(acc[rt][cc][r] + b2c[cc]);
      }
    __syncthreads();   // (d) emb ready

    // ---- logits via MFMA: wave wv handles query G*4+wv
    {
      int g = qbase + G * 4 + wv;
      int bb0 = (g >> 13) * NPTS;
      int idl = (int)idxp[(size_t)g * 16 + l15];
      float mvl = maskp[bb0 + idl];
      unsigned long long bm = __ballot(mvl > 0.0f);
      if (quad == 0) idS[wv * 16 + l15] = idl;
      const u16t* krow = kbuf + (size_t)(bb0 + idl) * DMODEL;
      const u16t* erow = hemb + (wv * 16 + l15) * HSTR;
      const u16t* qrow = qB + (G * 4 + wv) * HSTR;
      floatx4 sa = (floatx4){0.f, 0.f, 0.f, 0.f};
      #pragma unroll
      for (int ic = 0; ic < 8; ++ic) {
        short8 ak  = *(const short8*)(krow + ic * 32 + quad * 8);
        short8 ae  = *(const short8*)(erow + ic * 32 + quad * 8);
        short8 qb8 = *(const short8*)(qrow + ic * 32 + quad * 8);
        sa = __builtin_amdgcn_mfma_f32_16x16x32_bf16(ak, qb8, sa, 0, 0, 0);
        sa = __builtin_amdgcn_mfma_f32_16x16x32_bf16(ae, qb8, sa, 0, 0, 0);
      }
      // per-wave softmax over the 16 rows (rows quad*4+r in this lane)
      float lg[4];
      #pragma unroll
      for (int r = 0; r < 4; ++r) {
        int j = quad * 4 + r;
        lg[r] = ((bm >> j) & 1ULL) ? sa[r] * lsc : -1e30f;
      }
      float m = fmaxf(fmaxf(lg[0], lg[1]), fmaxf(lg[2], lg[3]));
      m = fmaxf(m, __shfl_xor(m, 16));
      m = fmaxf(m, __shfl_xor(m, 32));
      float e0 = __expf(lg[0] - m), e1 = __expf(lg[1] - m);
      float e2 = __expf(lg[2] - m), e3 = __expf(lg[3] - m);
      float s = e0 + e1 + e2 + e3;
      s += __shfl_xor(s, 16);
      s += __shfl_xor(s, 32);
      float inv = (m > -1e29f) ? __builtin_amdgcn_rcpf(s) : 0.0f;
      if (l15 == 0) {
        wS[wv * 16 + quad * 4 + 0] = e0 * inv;
        wS[wv * 16 + quad * 4 + 1] = e1 * inv;
        wS[wv * 16 + quad * 4 + 2] = e2 * inv;
        wS[wv * 16 + quad * 4 + 3] = e3 * inv;
      }
    }
    __syncthreads();   // (e) weights + ids ready

    // ---- PV per-thread (d = c)
    #pragma unroll
    for (int ql = 0; ql < 4; ++ql) {
      int g = qbase + G * 4 + ql;
      int bb0 = (g >> 13) * NPTS;
      float o = 0.0f;
      #pragma unroll
      for (int j = 0; j < 16; ++j) {
        int id  = idS[ql * 16 + j];
        float w = wS[ql * 16 + j];
        float vv = b2f(vbuf[(size_t)(bb0 + id) * DMODEL + c]);
        float ee = b2f(hemb[(ql * 16 + j) * HSTR + c]);
        o += w * (vv + ee);
      }
      outp[(size_t)g * DMODEL + c] = o;
    }
    if (G == 0) __syncthreads();   // (a') hemb reads done before next gelu
  }
}

// --------------------------------------------- out projection + LayerNorm
__global__ __launch_bounds__(256) void gemm_out(const float* __restrict__ feat,
    const float* __restrict__ maskp,
    const u16t* __restrict__ wofrag, const float* __restrict__ bo,
    const float* __restrict__ gamma, const float* __restrict__ beta,
    float* __restrict__ io) {
  int rbase = blockIdx.x * 64;
  int tid = threadIdx.x, lane = tid & 63, wvi = tid >> 6;
  int quad = lane >> 4, l15 = lane & 15;

  alignas(16) __shared__ u16t oS[64 * HSTR];

  {
    int r = tid >> 2, c0 = (tid & 3) * 64;
    const float* src = io + (size_t)(rbase + r) * DMODEL + c0;
    u16t* dst = oS + r * HSTR + c0;
    #pragma unroll
    for (int t = 0; t < 8; ++t) {
      float4 a = *(const float4*)(src + t * 8);
      float4 b = *(const float4*)(src + t * 8 + 4);
      float o[8] = {a.x, a.y, a.z, a.w, b.x, b.y, b.z, b.w};
      *(uint4*)(dst + t * 8) = pack8(o);
    }
  }
  __syncthreads();

  floatx4 acc[16];
  #pragma unroll
  for (int ct = 0; ct < 16; ++ct) acc[ct] = (floatx4){0.f, 0.f, 0.f, 0.f};

  #pragma unroll
  for (int ic = 0; ic < 8; ++ic) {
    short8 af = *(const short8*)(oS + (wvi * 16 + l15) * HSTR + ic * 32 + quad * 8);
    #pragma unroll
    for (int ct = 0; ct < 16; ++ct) {
      short8 bf = *(const short8*)(wofrag + (((size_t)(ic * 16 + ct) * 64 + lane) << 3));
      acc[ct] = __builtin_amdgcn_mfma_f32_16x16x32_bf16(af, bf, acc[ct], 0, 0, 0);
    }
  }

  float bov[16], gamv[16], betv[16];
  #pragma unroll
  for (int ct = 0; ct < 16; ++ct) {
    int col = ct * 16 + l15;
    bov[ct]  = bo[col];
    gamv[ct] = gamma[col];
    betv[ct] = beta[col];
  }

  #pragma unroll
  for (int r = 0; r < 4; ++r) {
    int row = rbase + wvi * 16 + quad * 4 + r;
    float mv = maskp[row];
    float hv[16];
    float s = 0.0f, s2 = 0.0f;
    #pragma unroll
    for (int ct = 0; ct < 16; ++ct) {
      float h = feat[(size_t)row * DMODEL + ct * 16 + l15] + (acc[ct][r] + bov[ct]) * mv;
      hv[ct] = h; s += h; s2 += h * h;
    }
    #pragma unroll
    for (int off = 1; off < 16; off <<= 1) {
      s  += __shfl_xor(s,  off, 16);
      s2 += __shfl_xor(s2, off, 16);
    }
    float mu  = s  * (1.0f / 256.0f);
    float ms  = s2 * (1.0f / 256.0f);
    float var = ms - mu * mu;
    float inv = 1.0f / sqrtf(var + 1e-6f);
    #pragma unroll
    for (int ct = 0; ct < 16; ++ct) {
      float y = (hv[ct] - mu) * inv * gamv[ct] + betv[ct];
      y *= mv;
      io[(size_t)row * DMODEL + ct * 16 + l15] = y;
    }
  }
}

// ---------------------------------------------------------------------- host
extern "C" void kernel_launch(void* const* d_in, const int* in_sizes, int n_in,
                              void* d_out, int out_size, void* d_ws, size_t ws_size,
                              hipStream_t stream) {
  static const int EXP[18] = {4194304, 49152, 49152, 16384,
                              65536, 256, 65536, 256, 65536, 256, 65536, 256,
                              1536, 256, 65536, 256, 256, 256};
  bool sizes_ok = (n_in >= 18);
  if (sizes_ok) for (int i = 0; i < 18; ++i) sizes_ok = sizes_ok && (in_sizes[i] == EXP[i]);
  int fb = (out_size + 255) / 256;
  if (!sizes_ok) {
    fill_valf<<<fb, 256, 0, stream>>>((float*)d_out, out_size, 0.0f);
    return;
  }
  const size_t WS_NEED = 17825792;
  if (ws_size < WS_NEED) {
    fill_valf<<<fb, 256, 0, stream>>>((float*)d_out, out_size, 1.0f);
    return;
  }

  const float* feat    = (const float*)d_in[0];
  const float* coords  = (const float*)d_in[1];
  const float* normals = (const float*)d_in[2];
  const float* maskp   = (const float*)d_in[3];
  const float* Wq  = (const float*)d_in[4];
  const float* bq  = (const float*)d_in[5];
  const float* Wk  = (const float*)d_in[6];
  const float* bk  = (const float*)d_in[7];
  const float* Wv  = (const float*)d_in[8];
  const float* bv  = (const float*)d_in[9];
  const float* Wo  = (const float*)d_in[10];
  const float* bo  = (const float*)d_in[11];
  const float* Wp1 = (const float*)d_in[12];
  const float* bp1 = (const float*)d_in[13];
  const float* Wp2 = (const float*)d_in[14];
  const float* bp2 = (const float*)d_in[15];
  const float* gamma = (const float*)d_in[16];
  const float* beta  = (const float*)d_in[17];

  // Workspace (= 17,825,792 B exactly):
  //   idx16 : u16 [16384*16]      @ 0          (524,288)
  //   frags : bf16 [4*65536]      @ 524,288    (524,288)  (Wk,Wv,Wp2,Wq)
  //   kb    : bf16 [16384*256]    @ 1,048,576  (8,388,608)
  //   vb    : bf16 [16384*256]    @ 9,437,184  (8,388,608)  end 17,825,792
  //   pk (kNN u64 partials, 16 MB) aliases kb+vb: dead before gemm_kv_mfma.
  //   wofrag (Wo frags, 128 KB) aliases kb: packed AFTER attn_mega (kb dead).
  char* ws = (char*)d_ws;
  u16t*  idx16  = (u16t*)(ws);
  u16t*  frags  = (u16t*)(ws + 524288);
  u16t*  kb     = (u16t*)(ws + 1048576);
  u16t*  vb     = (u16t*)(ws + 9437184);
  u64t*  pk     = (u64t*)(ws + 1048576);
  u16t*  wofrag = (u16t*)(ws + 1048576);

  wprep4<<<1024, 256, 0, stream>>>(Wk, Wv, Wp2, Wq, frags);
  knn_partial<<<512, 256, 0, stream>>>(coords, pk);
  knn_merge<<<64, 256, 0, stream>>>(pk, idx16);
  gemm_kv_mfma<<<512, 256, 0, stream>>>(feat, frags, bk, bv, kb, vb);
  attn_mega<<<2048, 256, 0, stream>>>(coords, normals, maskp, feat,
                                      bq, Wp1, bp1, bp2,
                                      idx16, frags + 196608, frags + 131072,
                                      kb, vb, (float*)d_out);
  wprep1<<<256, 256, 0, stream>>>(Wo, wofrag);   // kb dead after attn_mega
  gemm_out<<<256, 256, 0, stream>>>(feat, maskp, wofrag, bo, gamma, beta,
                                    (float*)d_out);
}